// Round 4
// baseline (449.721 us; speedup 1.0000x reference)
//
#include <hip/hip_runtime.h>

#define NNODES 50000
#define DIM 128

// ===========================================================================
// CSR build (per call; graph static within a call, reused by both layers)
// ===========================================================================

__global__ __launch_bounds__(256) void k_hist(
    const int* __restrict__ dst, int* __restrict__ counts, int n_edges)
{
    int e = blockIdx.x * blockDim.x + threadIdx.x;
    if (e >= n_edges) return;
    atomicAdd(&counts[dst[e]], 1);
}

// Exclusive scan, single workgroup of 1024, 4 ints/thread (int4).
__global__ __launch_bounds__(1024) void k_scan(
    const int* __restrict__ counts, int* __restrict__ rowptr, int n)
{
    __shared__ int wsum[16];
    __shared__ int running_s;
    const int lane = threadIdx.x & 63;
    const int wid = threadIdx.x >> 6;
    if (threadIdx.x == 0) running_s = 0;
    __syncthreads();
    const int ntot = (n + 4095) & ~4095;
    for (int base = 0; base < ntot; base += 4096) {
        int i = base + threadIdx.x * 4;
        int4 v = make_int4(0, 0, 0, 0);
        if (i + 3 < n) {
            v = *reinterpret_cast<const int4*>(counts + i);
        } else {
            if (i + 0 < n) v.x = counts[i + 0];
            if (i + 1 < n) v.y = counts[i + 1];
            if (i + 2 < n) v.z = counts[i + 2];
        }
        int tot = v.x + v.y + v.z + v.w;
        int s = tot;
#pragma unroll
        for (int off = 1; off < 64; off <<= 1) {
            int t = __shfl_up(s, off);
            if (lane >= off) s += t;
        }
        if (lane == 63) wsum[wid] = s;
        __syncthreads();
        if (wid == 0 && lane < 16) {
            int ws = wsum[lane];
#pragma unroll
            for (int off = 1; off < 16; off <<= 1) {
                int t = __shfl_up(ws, off);
                if (lane >= off) ws += t;
            }
            wsum[lane] = ws;
        }
        __syncthreads();
        int prefix = running_s + ((wid > 0) ? wsum[wid - 1] : 0) + (s - tot);
        int4 o;
        o.x = prefix;
        o.y = prefix + v.x;
        o.z = o.y + v.y;
        o.w = o.z + v.z;
        if (i + 3 < n) {
            *reinterpret_cast<int4*>(rowptr + i) = o;
        } else {
            if (i + 0 < n) rowptr[i + 0] = o.x;
            if (i + 1 < n) rowptr[i + 1] = o.y;
            if (i + 2 < n) rowptr[i + 2] = o.z;
        }
        __syncthreads();
        if (threadIdx.x == 1023) running_s += wsum[15];
        __syncthreads();
    }
    if (threadIdx.x == 0) rowptr[n] = running_s;
}

__global__ __launch_bounds__(256) void k_place(
    const int* __restrict__ src, const int* __restrict__ dst,
    const int* __restrict__ rowptr, int* __restrict__ cursor,
    int* __restrict__ srcs_sorted, int n_edges)
{
    int e = blockIdx.x * blockDim.x + threadIdx.x;
    if (e >= n_edges) return;
    int d = dst[e];
    int pos = rowptr[d] + atomicAdd(&cursor[d], 1);
    srcs_sorted[pos] = src[e];
}

// ===========================================================================
// Gather-sum: agg[n,:] = sum_{e in CSR row n} x[srcs[e], :]
// 32 threads/node (one float4 lane each); unroll-4 for MLP.
// ===========================================================================
__global__ __launch_bounds__(256) void k_gather_sum(
    const float* __restrict__ x, const int* __restrict__ rowptr,
    const int* __restrict__ srcs, float* __restrict__ agg)
{
    int g = blockIdx.x * 8 + (threadIdx.x >> 5);
    if (g >= NNODES) return;
    int d4 = threadIdx.x & 31;
    int beg = rowptr[g], end = rowptr[g + 1];
    float4 acc = make_float4(0.f, 0.f, 0.f, 0.f);
    int e = beg;
    for (; e + 3 < end; e += 4) {
        int s0 = srcs[e], s1 = srcs[e + 1], s2 = srcs[e + 2], s3 = srcs[e + 3];
        float4 v0 = reinterpret_cast<const float4*>(x)[(size_t)s0 * 32 + d4];
        float4 v1 = reinterpret_cast<const float4*>(x)[(size_t)s1 * 32 + d4];
        float4 v2 = reinterpret_cast<const float4*>(x)[(size_t)s2 * 32 + d4];
        float4 v3 = reinterpret_cast<const float4*>(x)[(size_t)s3 * 32 + d4];
        acc.x += v0.x + v1.x + v2.x + v3.x;
        acc.y += v0.y + v1.y + v2.y + v3.y;
        acc.z += v0.z + v1.z + v2.z + v3.z;
        acc.w += v0.w + v1.w + v2.w + v3.w;
    }
    for (; e < end; ++e) {
        int s0 = srcs[e];
        float4 v0 = reinterpret_cast<const float4*>(x)[(size_t)s0 * 32 + d4];
        acc.x += v0.x; acc.y += v0.y; acc.z += v0.z; acc.w += v0.w;
    }
    reinterpret_cast<float4*>(agg)[(size_t)g * 32 + d4] = acc;
}

// ===========================================================================
// Fused dual GEMM: C[n,h] = act( dot(A[n,:],Wa[h,:]) + dot(B[n,:],Wb[h,:]) + b[h] )
// k-major As -> a-fragment is a single ds_read_b128 (row stride BM+4 keeps
// 16B alignment; 2-way bank aliasing only). Register prefetch of chunk k+1's
// global loads during chunk k's compute hides vmcnt behind 32 d-steps of FMA.
// Chunk loop stays "#pragma unroll 1" (full unroll spilled in R1: 6 GB scratch).
// ===========================================================================
template <int BN, bool RELU>
__global__ __launch_bounds__(256) void k_dual_gemm(
    const float* __restrict__ A, const float* __restrict__ B,
    const float* __restrict__ Wa, const float* __restrict__ Wb,
    const float* __restrict__ bias, float* __restrict__ C, int n_nodes)
{
    constexpr int BM = 64, BK = 32;
    constexpr int TM = 4;
    constexpr int TN = BN / 16;            // 8 (BN=128) or 4 (BN=64)
    __shared__ float As[BK][BM + 4];       // k-major; stride 68 words
    __shared__ float Ws[BK][BN];           // Ws[k][h]

    const int tid = threadIdx.x;
    const int r = tid & 15;
    const int c = tid >> 4;
    const int n0 = blockIdx.x * BM;

    float acc[TM][TN];
#pragma unroll
    for (int i = 0; i < TM; ++i)
#pragma unroll
        for (int j = 0; j < TN; ++j) acc[i][j] = 0.f;

    const int lm = tid >> 2;               // node row in tile (0..63)
    const int lk = (tid & 3) * 8;          // k start for A staging
    constexpr int WL = (BK * BN) / 256;    // 16 or 8
    constexpr int KSPLIT = BK / WL;        // 2 or 4
    const int wh = tid / KSPLIT;
    const int wk = (tid % KSPLIT) * WL;

    const bool row_ok = (n0 + lm) < n_nodes;

    float4 pa0, pa1;                       // prefetched A regs
    float pw[WL];                          // prefetched W regs

    auto load_global = [&](int chunk) {
        const float* __restrict__ Ain = (chunk < 4) ? A : B;
        const float* __restrict__ Win = (chunk < 4) ? Wa : Wb;
        const int kb = (chunk & 3) * BK;
        pa0 = make_float4(0.f, 0.f, 0.f, 0.f);
        pa1 = pa0;
        if (row_ok) {
            const float4* gp = reinterpret_cast<const float4*>(
                Ain + (size_t)(n0 + lm) * DIM + kb + lk);
            pa0 = gp[0];
            pa1 = gp[1];
        }
#pragma unroll
        for (int i = 0; i < WL; i += 4) {
            float4 v = *reinterpret_cast<const float4*>(
                Win + (size_t)wh * DIM + kb + wk + i);
            pw[i + 0] = v.x; pw[i + 1] = v.y; pw[i + 2] = v.z; pw[i + 3] = v.w;
        }
    };
    auto store_lds = [&]() {
        As[lk + 0][lm] = pa0.x; As[lk + 1][lm] = pa0.y;
        As[lk + 2][lm] = pa0.z; As[lk + 3][lm] = pa0.w;
        As[lk + 4][lm] = pa1.x; As[lk + 5][lm] = pa1.y;
        As[lk + 6][lm] = pa1.z; As[lk + 7][lm] = pa1.w;
#pragma unroll
        for (int i = 0; i < WL; ++i) Ws[wk + i][wh] = pw[i];
    };

    load_global(0);
    store_lds();
    __syncthreads();

#pragma unroll 1
    for (int chunk = 0; chunk < 8; ++chunk) {
        if (chunk < 7) load_global(chunk + 1);   // in flight during compute
#pragma unroll
        for (int d = 0; d < BK; ++d) {
            float4 av = *reinterpret_cast<const float4*>(&As[d][r * 4]);
            float a[4] = {av.x, av.y, av.z, av.w};
            float w[TN];
#pragma unroll
            for (int j = 0; j < TN; j += 4) {
                float4 wv = *reinterpret_cast<const float4*>(&Ws[d][c * TN + j]);
                w[j + 0] = wv.x; w[j + 1] = wv.y;
                w[j + 2] = wv.z; w[j + 3] = wv.w;
            }
#pragma unroll
            for (int i = 0; i < TM; ++i)
#pragma unroll
                for (int j = 0; j < TN; ++j)
                    acc[i][j] = fmaf(a[i], w[j], acc[i][j]);
        }
        __syncthreads();
        if (chunk < 7) store_lds();
        __syncthreads();
    }

    float bv[TN];
#pragma unroll
    for (int j = 0; j < TN; ++j) bv[j] = bias[c * TN + j];
#pragma unroll
    for (int i = 0; i < TM; ++i) {
        int n = n0 + r * TM + i;
        if (n >= n_nodes) continue;
#pragma unroll
        for (int j = 0; j < TN; j += 4) {
            float4 o;
            o.x = acc[i][j + 0] + bv[j + 0];
            o.y = acc[i][j + 1] + bv[j + 1];
            o.z = acc[i][j + 2] + bv[j + 2];
            o.w = acc[i][j + 3] + bv[j + 3];
            if (RELU) {
                o.x = fmaxf(o.x, 0.f); o.y = fmaxf(o.y, 0.f);
                o.z = fmaxf(o.z, 0.f); o.w = fmaxf(o.w, 0.f);
            }
            *reinterpret_cast<float4*>(C + (size_t)n * BN + c * TN + j) = o;
        }
    }
}

extern "C" void kernel_launch(void* const* d_in, const int* in_sizes, int n_in,
                              void* d_out, int out_size, void* d_ws, size_t ws_size,
                              hipStream_t stream) {
    const float* x       = (const float*)d_in[0];
    const int*   ei      = (const int*)d_in[1];
    const float* W_rel1  = (const float*)d_in[2];
    const float* W_root1 = (const float*)d_in[3];
    const float* b1      = (const float*)d_in[4];
    const float* W_rel2  = (const float*)d_in[5];
    const float* W_root2 = (const float*)d_in[6];
    const float* b2      = (const float*)d_in[7];

    const int n_edges = in_sizes[1] / 2;
    const int* src = ei;
    const int* dst = ei + n_edges;

    // workspace layout (cursor kept 16B-aligned for int4 scan loads)
    float* agg  = (float*)d_ws;                           // 6.4M floats
    float* t    = agg + (size_t)NNODES * DIM;             // 6.4M floats
    int* rowptr = (int*)(t + (size_t)NNODES * DIM);       // NNODES+4 (padded)
    int* cursor = rowptr + (NNODES + 4);                  // NNODES
    int* srcs   = cursor + NNODES;                        // n_edges

    float* out = (float*)d_out;

    const int eblocks = (n_edges + 255) / 256;
    const int gblocks = (NNODES + 7) / 8;
    const int gemm_blocks = (NNODES + 63) / 64;

    // ---- CSR build (once; reused by both layers) ----
    hipMemsetAsync(cursor, 0, NNODES * sizeof(int), stream);
    k_hist<<<eblocks, 256, 0, stream>>>(dst, cursor, n_edges);
    k_scan<<<1, 1024, 0, stream>>>(cursor, rowptr, NNODES);
    hipMemsetAsync(cursor, 0, NNODES * sizeof(int), stream);
    k_place<<<eblocks, 256, 0, stream>>>(src, dst, rowptr, cursor, srcs, n_edges);

    // ---- layer 1 ----
    k_gather_sum<<<gblocks, 256, 0, stream>>>(x, rowptr, srcs, agg);
    k_dual_gemm<128, true><<<gemm_blocks, 256, 0, stream>>>(
        agg, x, W_rel1, W_root1, b1, t, NNODES);

    // ---- layer 2 ----
    k_gather_sum<<<gblocks, 256, 0, stream>>>(t, rowptr, srcs, agg);
    k_dual_gemm<64, false><<<gemm_blocks, 256, 0, stream>>>(
        agg, t, W_rel2, W_root2, b2, out, NNODES);
}

// Round 5
// 269.524 us; speedup vs baseline: 1.6686x; 1.6686x over previous
//
#include <hip/hip_runtime.h>

#define NNODES 50000
#define DIM 128

typedef __attribute__((ext_vector_type(8))) __bf16 bf16x8;
typedef __attribute__((ext_vector_type(4))) float f32x4;

__device__ inline unsigned short f2b(float f) {           // RNE fp32->bf16
    unsigned int u = __float_as_uint(f);
    u += 0x7fffu + ((u >> 16) & 1u);
    return (unsigned short)(u >> 16);
}
__device__ inline float blo(unsigned int u) { return __uint_as_float(u << 16); }
__device__ inline float bhi(unsigned int u) { return __uint_as_float(u & 0xffff0000u); }
__device__ inline unsigned int pack2(float a, float b) {
    return (unsigned int)f2b(a) | ((unsigned int)f2b(b) << 16);
}

// ===========================================================================
// Casts (once per call)
// ===========================================================================
__global__ __launch_bounds__(256) void k_cast_f4(
    const float* __restrict__ src, unsigned short* __restrict__ dst, int n4)
{
    int i = blockIdx.x * 256 + threadIdx.x;
    if (i >= n4) return;
    float4 v = reinterpret_cast<const float4*>(src)[i];
    uint2 o;
    o.x = pack2(v.x, v.y);
    o.y = pack2(v.z, v.w);
    reinterpret_cast<uint2*>(dst)[i] = o;
}

__global__ __launch_bounds__(256) void k_cast_weights(
    const float* __restrict__ Wa1, const float* __restrict__ Wb1,
    const float* __restrict__ Wa2, const float* __restrict__ Wb2,
    unsigned short* __restrict__ wa1, unsigned short* __restrict__ wb1,
    unsigned short* __restrict__ wa2, unsigned short* __restrict__ wb2)
{
    int i = blockIdx.x * 256 + threadIdx.x;
    if (i < 16384) { wa1[i] = f2b(Wa1[i]); wb1[i] = f2b(Wb1[i]); }
    if (i < 8192)  { wa2[i] = f2b(Wa2[i]); wb2[i] = f2b(Wb2[i]); }
}

// ===========================================================================
// CSR build (per call; graph static within a call, reused by both layers)
// ===========================================================================
__global__ __launch_bounds__(256) void k_hist(
    const int* __restrict__ dst, int* __restrict__ counts, int n_edges)
{
    int e = blockIdx.x * blockDim.x + threadIdx.x;
    if (e >= n_edges) return;
    atomicAdd(&counts[dst[e]], 1);
}

__global__ __launch_bounds__(1024) void k_scan(
    const int* __restrict__ counts, int* __restrict__ rowptr, int n)
{
    __shared__ int wsum[16];
    __shared__ int running_s;
    const int lane = threadIdx.x & 63;
    const int wid = threadIdx.x >> 6;
    if (threadIdx.x == 0) running_s = 0;
    __syncthreads();
    const int ntot = (n + 4095) & ~4095;
    for (int base = 0; base < ntot; base += 4096) {
        int i = base + threadIdx.x * 4;
        int4 v = make_int4(0, 0, 0, 0);
        if (i + 3 < n) {
            v = *reinterpret_cast<const int4*>(counts + i);
        } else {
            if (i + 0 < n) v.x = counts[i + 0];
            if (i + 1 < n) v.y = counts[i + 1];
            if (i + 2 < n) v.z = counts[i + 2];
        }
        int tot = v.x + v.y + v.z + v.w;
        int s = tot;
#pragma unroll
        for (int off = 1; off < 64; off <<= 1) {
            int t = __shfl_up(s, off);
            if (lane >= off) s += t;
        }
        if (lane == 63) wsum[wid] = s;
        __syncthreads();
        if (wid == 0 && lane < 16) {
            int ws = wsum[lane];
#pragma unroll
            for (int off = 1; off < 16; off <<= 1) {
                int t = __shfl_up(ws, off);
                if (lane >= off) ws += t;
            }
            wsum[lane] = ws;
        }
        __syncthreads();
        int prefix = running_s + ((wid > 0) ? wsum[wid - 1] : 0) + (s - tot);
        int4 o;
        o.x = prefix;
        o.y = prefix + v.x;
        o.z = o.y + v.y;
        o.w = o.z + v.z;
        if (i + 3 < n) {
            *reinterpret_cast<int4*>(rowptr + i) = o;
        } else {
            if (i + 0 < n) rowptr[i + 0] = o.x;
            if (i + 1 < n) rowptr[i + 1] = o.y;
            if (i + 2 < n) rowptr[i + 2] = o.z;
        }
        __syncthreads();
        if (threadIdx.x == 1023) running_s += wsum[15];
        __syncthreads();
    }
    if (threadIdx.x == 0) rowptr[n] = running_s;
}

__global__ __launch_bounds__(256) void k_place(
    const int* __restrict__ src, const int* __restrict__ dst,
    const int* __restrict__ rowptr, int* __restrict__ cursor,
    int* __restrict__ srcs_sorted, int n_edges)
{
    int e = blockIdx.x * blockDim.x + threadIdx.x;
    if (e >= n_edges) return;
    int d = dst[e];
    int pos = rowptr[d] + atomicAdd(&cursor[d], 1);
    srcs_sorted[pos] = src[e];
}

// ===========================================================================
// Gather-sum (bf16 in / bf16 out, fp32 accumulate):
// 16 lanes per node, each owns 8 contiguous bf16 (16 B); row read = 256 B.
// ===========================================================================
__global__ __launch_bounds__(256) void k_gather_sum(
    const unsigned short* __restrict__ xb, const int* __restrict__ rowptr,
    const int* __restrict__ srcs, unsigned short* __restrict__ aggb)
{
    int node = blockIdx.x * 16 + (threadIdx.x >> 4);
    if (node >= NNODES) return;
    int seg = threadIdx.x & 15;                 // 8-elem segment within row
    int beg = rowptr[node], end = rowptr[node + 1];
    float acc[8];
#pragma unroll
    for (int i = 0; i < 8; ++i) acc[i] = 0.f;
    int e = beg;
    for (; e + 3 < end; e += 4) {
#pragma unroll
        for (int u = 0; u < 4; ++u) {
            int s = srcs[e + u];
            uint4 v = *reinterpret_cast<const uint4*>(xb + (size_t)s * DIM + seg * 8);
            acc[0] += blo(v.x); acc[1] += bhi(v.x);
            acc[2] += blo(v.y); acc[3] += bhi(v.y);
            acc[4] += blo(v.z); acc[5] += bhi(v.z);
            acc[6] += blo(v.w); acc[7] += bhi(v.w);
        }
    }
    for (; e < end; ++e) {
        int s = srcs[e];
        uint4 v = *reinterpret_cast<const uint4*>(xb + (size_t)s * DIM + seg * 8);
        acc[0] += blo(v.x); acc[1] += bhi(v.x);
        acc[2] += blo(v.y); acc[3] += bhi(v.y);
        acc[4] += blo(v.z); acc[5] += bhi(v.z);
        acc[6] += blo(v.w); acc[7] += bhi(v.w);
    }
    uint4 o;
    o.x = pack2(acc[0], acc[1]);
    o.y = pack2(acc[2], acc[3]);
    o.z = pack2(acc[4], acc[5]);
    o.w = pack2(acc[6], acc[7]);
    *reinterpret_cast<uint4*>(aggb + (size_t)node * DIM + seg * 8) = o;
}

// ===========================================================================
// MFMA dual GEMM: C[n,h] = act( [agg|root] @ [Wa;Wb]^T + bias )
// 16x16x32 bf16 MFMA. Block = 256 thr = 4 waves; BM=64 (16 rows/wave),
// BK=64 (2 mfma K-steps per chunk), 4 chunks (2 per operand half).
// LDS rows padded to 72 bf16 (144 B): 16B-aligned, 2-way bank alias max.
// A/B frag: lane(l16=l&15, quad=l>>4) reads tile[l16_row][quad*8..+7] as b128.
// C/D frag: col=l16, row=quad*4+reg (m89-verified mapping).
// ===========================================================================
template <int BN, bool RELU, bool OUTBF16>
__global__ __launch_bounds__(256) void k_dual_gemm_mfma(
    const unsigned short* __restrict__ Ab,   // agg   [n,128] bf16
    const unsigned short* __restrict__ Bb,   // root  [n,128] bf16
    const unsigned short* __restrict__ Wa,   // [BN,128] bf16
    const unsigned short* __restrict__ Wb,   // [BN,128] bf16
    const float* __restrict__ bias,
    void* __restrict__ Cout, int n_nodes)
{
    constexpr int BM = 64, LDT = 72;         // 64 k + 8 pad (bf16 units)
    constexpr int NT = BN / 16;              // 8 (layer1) or 4 (layer2)
    __shared__ unsigned short As[BM * LDT];
    __shared__ unsigned short Bs[BN * LDT];

    const int tid = threadIdx.x;
    const int wave = tid >> 6;
    const int lane = tid & 63;
    const int quad = lane >> 4;
    const int l16 = lane & 15;
    const int n0 = blockIdx.x * BM;

    f32x4 acc[NT];
#pragma unroll
    for (int nt = 0; nt < NT; ++nt) {
        f32x4 z = {0.f, 0.f, 0.f, 0.f};
        acc[nt] = z;
    }

#pragma unroll 1
    for (int chunk = 0; chunk < 4; ++chunk) {
        const unsigned short* __restrict__ Asrc = (chunk < 2) ? Ab : Bb;
        const unsigned short* __restrict__ Wsrc = (chunk < 2) ? Wa : Wb;
        const int kb = (chunk & 1) * 64;

        __syncthreads();
        // stage A tile: 64 rows x 8 segs (16 B each) = 512 segs / 256 thr
#pragma unroll
        for (int s = tid; s < BM * 8; s += 256) {
            int row = s >> 3, sg = s & 7;
            uint4 v = make_uint4(0u, 0u, 0u, 0u);
            if (n0 + row < n_nodes)
                v = *reinterpret_cast<const uint4*>(
                    Asrc + (size_t)(n0 + row) * DIM + kb + sg * 8);
            *reinterpret_cast<uint4*>(&As[row * LDT + sg * 8]) = v;
        }
        // stage B tile (weights are already [h][k] row-major = B^T layout)
#pragma unroll
        for (int s = tid; s < BN * 8; s += 256) {
            int row = s >> 3, sg = s & 7;
            uint4 v = *reinterpret_cast<const uint4*>(
                Wsrc + (size_t)row * DIM + kb + sg * 8);
            *reinterpret_cast<uint4*>(&Bs[row * LDT + sg * 8]) = v;
        }
        __syncthreads();

#pragma unroll
        for (int ks = 0; ks < 2; ++ks) {
            bf16x8 a = *reinterpret_cast<const bf16x8*>(
                &As[(wave * 16 + l16) * LDT + ks * 32 + quad * 8]);
#pragma unroll
            for (int nt = 0; nt < NT; ++nt) {
                bf16x8 b = *reinterpret_cast<const bf16x8*>(
                    &Bs[(nt * 16 + l16) * LDT + ks * 32 + quad * 8]);
                acc[nt] = __builtin_amdgcn_mfma_f32_16x16x32_bf16(a, b, acc[nt], 0, 0, 0);
            }
        }
    }

    // epilogue: C row = n0 + wave*16 + quad*4 + reg, col = nt*16 + l16
#pragma unroll
    for (int nt = 0; nt < NT; ++nt) {
        int col = nt * 16 + l16;
        float bv = bias[col];
#pragma unroll
        for (int reg = 0; reg < 4; ++reg) {
            int row = n0 + wave * 16 + quad * 4 + reg;
            if (row >= n_nodes) continue;
            float v = acc[nt][reg] + bv;
            if (RELU) v = fmaxf(v, 0.f);
            if (OUTBF16)
                ((unsigned short*)Cout)[(size_t)row * BN + col] = f2b(v);
            else
                ((float*)Cout)[(size_t)row * BN + col] = v;
        }
    }
}

extern "C" void kernel_launch(void* const* d_in, const int* in_sizes, int n_in,
                              void* d_out, int out_size, void* d_ws, size_t ws_size,
                              hipStream_t stream) {
    const float* x       = (const float*)d_in[0];
    const int*   ei      = (const int*)d_in[1];
    const float* W_rel1  = (const float*)d_in[2];
    const float* W_root1 = (const float*)d_in[3];
    const float* b1      = (const float*)d_in[4];
    const float* W_rel2  = (const float*)d_in[5];
    const float* W_root2 = (const float*)d_in[6];
    const float* b2      = (const float*)d_in[7];

    const int n_edges = in_sizes[1] / 2;
    const int* src = ei;
    const int* dst = ei + n_edges;

    // workspace layout (all 16B-aligned)
    const size_t NELEM = (size_t)NNODES * DIM;            // 6.4M
    unsigned short* xb   = (unsigned short*)d_ws;         // 12.8 MB
    unsigned short* aggb = xb + NELEM;                    // 12.8 MB
    unsigned short* tb   = aggb + NELEM;                  // 12.8 MB
    unsigned short* wa1  = tb + NELEM;                    // 16384
    unsigned short* wb1  = wa1 + 16384;
    unsigned short* wa2  = wb1 + 16384;                   // 8192
    unsigned short* wb2  = wa2 + 8192;
    int* rowptr = (int*)(wb2 + 8192);                     // NNODES+4
    int* cursor = rowptr + (NNODES + 4);
    int* srcs   = cursor + NNODES;

    float* out = (float*)d_out;

    const int eblocks = (n_edges + 255) / 256;
    const int gblocks = (NNODES + 15) / 16;
    const int gemm_blocks = (NNODES + 63) / 64;
    const int n4 = NNODES * DIM / 4;

    // ---- casts ----
    k_cast_f4<<<(n4 + 255) / 256, 256, 0, stream>>>(x, xb, n4);
    k_cast_weights<<<64, 256, 0, stream>>>(W_rel1, W_root1, W_rel2, W_root2,
                                           wa1, wb1, wa2, wb2);

    // ---- CSR build ----
    hipMemsetAsync(cursor, 0, NNODES * sizeof(int), stream);
    k_hist<<<eblocks, 256, 0, stream>>>(dst, cursor, n_edges);
    k_scan<<<1, 1024, 0, stream>>>(cursor, rowptr, NNODES);
    hipMemsetAsync(cursor, 0, NNODES * sizeof(int), stream);
    k_place<<<eblocks, 256, 0, stream>>>(src, dst, rowptr, cursor, srcs, n_edges);

    // ---- layer 1 ----
    k_gather_sum<<<gblocks, 256, 0, stream>>>(xb, rowptr, srcs, aggb);
    k_dual_gemm_mfma<128, true, true><<<gemm_blocks, 256, 0, stream>>>(
        aggb, xb, wa1, wb1, b1, tb, NNODES);

    // ---- layer 2 ----
    k_gather_sum<<<gblocks, 256, 0, stream>>>(tb, rowptr, srcs, aggb);
    k_dual_gemm_mfma<64, false, false><<<gemm_blocks, 256, 0, stream>>>(
        aggb, tb, wa2, wb2, b2, out, NNODES);
}